// Round 3
// baseline (2246.105 us; speedup 1.0000x reference)
//
#include <hip/hip_runtime.h>
#include <hip/hip_bf16.h>

// LSTM encoder, two-phase.
// Phase 1 (xg_gemm, 2048 WGs, all CUs): xg[t][b][hh][g] = emb[tok]·Wih^T + b,
//   bf16, 134 MB in d_ws. Standard 16x16x32 MFMA, M=64 (batch) per WG (one t).
// Phase 2 (lstm_rec, 16 persistent WGs x 512 thr, 4 batch rows each): per step
//   gates = xg(prefetched global, depth-2) + h*Whh^T (128 MFMAs/WG), gate
//   compaction through LDS, one (row,hcol) activation per thread, c in fp32.
// Fallback single kernel if ws_size < 134 MB.

namespace {

constexpr int T_LEN = 2048;
constexpr int Bsz   = 64;
constexpr int Dd    = 128;
constexpr int Hh    = 128;
constexpr int Gg    = 512;
constexpr int NWG   = 16;
constexpr int BPW   = Bsz / NWG;  // 4
constexpr int NT    = 512;
constexpr int XS    = 136;   // LDS row stride in shorts

typedef __attribute__((ext_vector_type(8))) short   short8;
typedef __attribute__((ext_vector_type(4))) float   floatx4;
typedef __attribute__((ext_vector_type(2))) unsigned int uintx2;

#define MFMA16(a, b, c) __builtin_amdgcn_mfma_f32_16x16x32_bf16((a), (b), (c), 0, 0, 0)

__device__ __forceinline__ float sigmoidf_(float x) {
    return __builtin_amdgcn_rcpf(1.0f + __builtin_amdgcn_exp2f(x * -1.44269504f));
}
__device__ __forceinline__ float tanhf_(float x) {
    return __builtin_fmaf(-2.0f,
        __builtin_amdgcn_rcpf(1.0f + __builtin_amdgcn_exp2f(x * 2.88539008f)), 1.0f);
}
__device__ __forceinline__ unsigned short f2bf(float f) {
    __hip_bfloat16 h = __float2bfloat16(f);  // RNE
    union { __hip_bfloat16 b; unsigned short u; } v; v.b = h; return v.u;
}
__device__ __forceinline__ float bf2f(unsigned int lo16) {
    union { unsigned int u; float f; } v; v.u = lo16 << 16; return v.f;
}
__device__ __forceinline__ uintx2 f4bf(const float4 v) {
    union { unsigned short us[4]; uintx2 u2; } p;
    p.us[0] = f2bf(v.x); p.us[1] = f2bf(v.y); p.us[2] = f2bf(v.z); p.us[3] = f2bf(v.w);
    return p.u2;
}
__device__ __forceinline__ short8 ld8bf(const float* p) {
    const float4 a = *reinterpret_cast<const float4*>(p);
    const float4 b = *reinterpret_cast<const float4*>(p + 4);
    short8 s;
    s[0] = (short)f2bf(a.x); s[1] = (short)f2bf(a.y);
    s[2] = (short)f2bf(a.z); s[3] = (short)f2bf(a.w);
    s[4] = (short)f2bf(b.x); s[5] = (short)f2bf(b.y);
    s[6] = (short)f2bf(b.z); s[7] = (short)f2bf(b.w);
    return s;
}

// ---------------- Phase 1: xg = emb(tok) @ Wih^T + (bih+bhh), bf16 -----------
__global__ void xg_gemm(const int*   __restrict__ tokens,
                        const float* __restrict__ emb,
                        const float* __restrict__ Wih,
                        const float* __restrict__ bih,
                        const float* __restrict__ bhh,
                        unsigned short* __restrict__ xg)  // [T][64][128][4]
{
    __shared__ unsigned short albs[64 * XS];  // A tile: 64 batch rows x 128 bf16

    const int t    = blockIdx.x;
    const int tid  = threadIdx.x;
    const int w    = tid >> 6;
    const int l    = tid & 63;
    const int quad = l >> 4;
    const int cl   = l & 15;

    // stage A: 64 emb rows (one per batch), 8 threads/row x 16 floats
    {
        const int b = tid >> 3, seg = tid & 7;
        const int tok = tokens[b * T_LEN + t];
        const float* src = emb + (size_t)tok * Dd + seg * 16;
        short8 lo = ld8bf(src);
        short8 hi = ld8bf(src + 8);
        *reinterpret_cast<short8*>(&albs[b * XS + seg * 16])     = lo;
        *reinterpret_cast<short8*>(&albs[b * XS + seg * 16 + 8]) = hi;
    }

    // B fragments + bias: wave w owns gate cols n = q*128 + w*16 + cl
    short8 wf[4][4];
    float  bias[4];
#pragma unroll
    for (int q = 0; q < 4; ++q) {
        const int n = q * 128 + w * 16 + cl;
#pragma unroll
        for (int kk = 0; kk < 4; ++kk)
            wf[q][kk] = ld8bf(Wih + n * Dd + kk * 32 + quad * 8);
        bias[q] = bih[n] + bhh[n];
    }

    __syncthreads();

    floatx4 acc[4][4];  // [mt][q]
#pragma unroll
    for (int mt = 0; mt < 4; ++mt)
#pragma unroll
        for (int q = 0; q < 4; ++q)
            acc[mt][q] = (floatx4){0.f, 0.f, 0.f, 0.f};

#pragma unroll
    for (int kk = 0; kk < 4; ++kk) {
        short8 af[4];
#pragma unroll
        for (int mt = 0; mt < 4; ++mt)
            af[mt] = *reinterpret_cast<const short8*>(
                &albs[(mt * 16 + cl) * XS + kk * 32 + quad * 8]);
#pragma unroll
        for (int mt = 0; mt < 4; ++mt)
#pragma unroll
            for (int q = 0; q < 4; ++q)
                acc[mt][q] = MFMA16(af[mt], wf[q][kk], acc[mt][q]);
    }

    // epilogue: xg[t][m][hh][g], gates interleaved for one 8B load in phase 2
    const int hh = w * 16 + cl;
#pragma unroll
    for (int mt = 0; mt < 4; ++mt) {
#pragma unroll
        for (int r = 0; r < 4; ++r) {
            const int m = mt * 16 + quad * 4 + r;
            union { unsigned short us[4]; uintx2 u2; } p;
#pragma unroll
            for (int g = 0; g < 4; ++g)
                p.us[g] = f2bf(acc[mt][g][r] + bias[g]);
            *reinterpret_cast<uintx2*>(
                xg + ((size_t)t * Bsz + m) * Gg + hh * 4) = p.u2;
        }
    }
}

// ---------------- Phase 2: persistent recurrence -----------------------------
__global__ __launch_bounds__(NT, 2) void lstm_rec(
    const unsigned short* __restrict__ xg,   // [T][64][128][4] bf16
    const float* __restrict__ Whh,           // [512][128] fp32
    float*       __restrict__ out)           // [2][64][128] fp32
{
    __shared__ unsigned short hbuf[2][16 * XS];  // h tile bf16 (rows 4-15 stay 0)
    __shared__ float scratch[4 * Gg];            // gates fp32 [row r][gate n]

    const int tid  = threadIdx.x;
    const int w    = tid >> 6;
    const int l    = tid & 63;
    const int quad = l >> 4;
    const int cl   = l & 15;
    const int bbase = blockIdx.x * BPW;

    const int rr = tid >> 7;          // 0..3 batch row within WG
    const int hh = tid & 127;         // hidden col

    // Whh B-fragments (fp32 -> bf16 once)
    short8 whh_f[4][4];
#pragma unroll
    for (int q = 0; q < 4; ++q) {
        const int n = q * 128 + w * 16 + cl;
#pragma unroll
        for (int kk = 0; kk < 4; ++kk)
            whh_f[q][kk] = ld8bf(Whh + n * Hh + kk * 32 + quad * 8);
    }

    for (int i = tid; i < 16 * XS; i += NT) { hbuf[0][i] = 0; hbuf[1][i] = 0; }

    // xg prefetch, depth 2: xgp[t&1] holds xg for step t
    const size_t xbase = ((size_t)(bbase + rr)) * Gg + hh * 4;
    uintx2 xgp[2];
    xgp[0] = *reinterpret_cast<const uintx2*>(xg + xbase);
    xgp[1] = *reinterpret_cast<const uintx2*>(xg + (size_t)Bsz * Gg + xbase);

    __syncthreads();  // hbuf zeros visible

    const int afrag_el = cl * XS + quad * 8;  // + kk*32

    float c_state = 0.0f;
    float h_last  = 0.0f;

    for (int t = 0; t < T_LEN; ++t) {
        const int cur = t & 1, nxt = cur ^ 1;

        const uintx2 xv = xgp[cur];
        if (t + 2 < T_LEN)
            xgp[cur] = *reinterpret_cast<const uintx2*>(
                xg + ((size_t)(t + 2)) * Bsz * Gg + xbase);

        // h fragments (hbuf[cur] complete since last barrier)
        short8 hf[4];
#pragma unroll
        for (int kk = 0; kk < 4; ++kk)
            hf[kk] = *reinterpret_cast<const short8*>(&hbuf[cur][afrag_el + kk * 32]);

        floatx4 acc[4];
#pragma unroll
        for (int q = 0; q < 4; ++q) acc[q] = (floatx4){0.f, 0.f, 0.f, 0.f};
#pragma unroll
        for (int kk = 0; kk < 4; ++kk)
#pragma unroll
            for (int q = 0; q < 4; ++q)
                acc[q] = MFMA16(hf[kk], whh_f[q][kk], acc[q]);

        // compact valid rows (m = quad*4+r < 4 => quad==0)
        if (quad == 0) {
#pragma unroll
            for (int q = 0; q < 4; ++q) {
                const int n = q * 128 + w * 16 + cl;
#pragma unroll
                for (int r = 0; r < 4; ++r)
                    scratch[r * Gg + n] = acc[q][r];
            }
        }
        __syncthreads();  // barrier 1: gates ready

        // activations; gate order i,f,g,o packed in xv as (x:lo,hi)(y:lo,hi)
        {
            const float iv = scratch[rr * Gg + hh]       + bf2f(xv.x & 0xffffu);
            const float fv = scratch[rr * Gg + 128 + hh] + bf2f(xv.x >> 16);
            const float gv = scratch[rr * Gg + 256 + hh] + bf2f(xv.y & 0xffffu);
            const float ov = scratch[rr * Gg + 384 + hh] + bf2f(xv.y >> 16);
            const float si = sigmoidf_(iv);
            const float sf = sigmoidf_(fv);
            const float so = sigmoidf_(ov);
            const float tg = tanhf_(gv);
            c_state = sf * c_state + si * tg;
            h_last  = so * tanhf_(c_state);
            hbuf[nxt][rr * XS + hh] = f2bf(h_last);
        }
        __syncthreads();  // barrier 2: h(t+1) ready; scratch reusable
    }

    const int ob = (bbase + rr) * Hh + hh;
    out[ob]            = h_last;
    out[Bsz * Hh + ob] = c_state;
}

// ---------------- Fallback (R2 working kernel) if ws too small ---------------
__global__ __launch_bounds__(NT, 2) void lstm_fused_fb(
    const int*   __restrict__ tokens,
    const float* __restrict__ emb,
    const float* __restrict__ Wih,
    const float* __restrict__ Whh,
    const float* __restrict__ bih,
    const float* __restrict__ bhh,
    float*       __restrict__ out)
{
    __shared__ unsigned short xbuf[2][16 * XS];
    __shared__ unsigned short hbuf[2][16 * XS];
    __shared__ float scratch[4 * Gg];

    const int tid  = threadIdx.x;
    const int w    = tid >> 6;
    const int l    = tid & 63;
    const int quad = l >> 4;
    const int cl   = l & 15;
    const int bbase = blockIdx.x * BPW;
    const int rr = tid >> 7;
    const int hh = tid & 127;

    short8 wih[4][4], whh[4][4];
    float  bias[4];
#pragma unroll
    for (int q = 0; q < 4; ++q) {
        const int n = q * 128 + w * 16 + cl;
#pragma unroll
        for (int kk = 0; kk < 4; ++kk) {
            const int k0 = kk * 32 + quad * 8;
            wih[q][kk] = ld8bf(Wih + n * Dd + k0);
            whh[q][kk] = ld8bf(Whh + n * Hh + k0);
        }
        bias[q] = bih[n] + bhh[n];
    }

    for (int i = tid; i < 16 * XS; i += NT) {
        xbuf[0][i] = 0; xbuf[1][i] = 0; hbuf[0][i] = 0; hbuf[1][i] = 0;
    }

    const bool gact = (tid < 128);
    const int  gr = tid >> 5;
    const int  gp = tid & 31;
    float4 gdataf = {0.f, 0.f, 0.f, 0.f};
    if (gact) {
        const int tok = tokens[(bbase + gr) * T_LEN + 0];
        gdataf = *reinterpret_cast<const float4*>(emb + (size_t)tok * Dd + gp * 4);
    }
    __syncthreads();
    if (gact) *reinterpret_cast<uintx2*>(&xbuf[0][gr * XS + gp * 4]) = f4bf(gdataf);
    if (gact) {
        const int tok = tokens[(bbase + gr) * T_LEN + 1];
        gdataf = *reinterpret_cast<const float4*>(emb + (size_t)tok * Dd + gp * 4);
    }
    __syncthreads();

    const int afrag_el = cl * XS + quad * 8;

    floatx4 acc[4];
#pragma unroll
    for (int q = 0; q < 4; ++q) acc[q] = (floatx4){bias[q], bias[q], bias[q], bias[q]};
    {
        short8 xf[4];
#pragma unroll
        for (int kk = 0; kk < 4; ++kk)
            xf[kk] = *reinterpret_cast<const short8*>(&xbuf[0][afrag_el + kk * 32]);
#pragma unroll
        for (int kk = 0; kk < 4; ++kk)
#pragma unroll
            for (int q = 0; q < 4; ++q)
                acc[q] = MFMA16(xf[kk], wih[q][kk], acc[q]);
    }

    float c_state = 0.0f, h_last = 0.0f;

    for (int t = 0; t < T_LEN; ++t) {
        const int cur = t & 1, nxt = cur ^ 1;
        short8 hf[4];
#pragma unroll
        for (int kk = 0; kk < 4; ++kk)
            hf[kk] = *reinterpret_cast<const short8*>(&hbuf[cur][afrag_el + kk * 32]);
        if (gact && (t + 1 < T_LEN))
            *reinterpret_cast<uintx2*>(&xbuf[nxt][gr * XS + gp * 4]) = f4bf(gdataf);
        if (gact && (t + 2 < T_LEN)) {
            const int tok = tokens[(bbase + gr) * T_LEN + (t + 2)];
            gdataf = *reinterpret_cast<const float4*>(emb + (size_t)tok * Dd + gp * 4);
        }
#pragma unroll
        for (int kk = 0; kk < 4; ++kk)
#pragma unroll
            for (int q = 0; q < 4; ++q)
                acc[q] = MFMA16(hf[kk], whh[q][kk], acc[q]);
        if (quad == 0) {
#pragma unroll
            for (int q = 0; q < 4; ++q) {
                const int n = q * 128 + w * 16 + cl;
#pragma unroll
                for (int r = 0; r < 4; ++r)
                    scratch[r * Gg + n] = acc[q][r];
            }
        }
        __syncthreads();
#pragma unroll
        for (int q = 0; q < 4; ++q) acc[q] = (floatx4){bias[q], bias[q], bias[q], bias[q]};
        if (t + 1 < T_LEN) {
            short8 xf[4];
#pragma unroll
            for (int kk = 0; kk < 4; ++kk)
                xf[kk] = *reinterpret_cast<const short8*>(&xbuf[nxt][afrag_el + kk * 32]);
#pragma unroll
            for (int kk = 0; kk < 4; ++kk)
#pragma unroll
                for (int q = 0; q < 4; ++q)
                    acc[q] = MFMA16(xf[kk], wih[q][kk], acc[q]);
        }
        {
            const float iv = scratch[rr * Gg + hh];
            const float fv = scratch[rr * Gg + 128 + hh];
            const float gv = scratch[rr * Gg + 256 + hh];
            const float ov = scratch[rr * Gg + 384 + hh];
            const float si = sigmoidf_(iv);
            const float sf = sigmoidf_(fv);
            const float so = sigmoidf_(ov);
            const float tg = tanhf_(gv);
            c_state = sf * c_state + si * tg;
            h_last  = so * tanhf_(c_state);
            hbuf[nxt][rr * XS + hh] = f2bf(h_last);
        }
        __syncthreads();
    }

    const int ob = (bbase + rr) * Hh + hh;
    out[ob]            = h_last;
    out[Bsz * Hh + ob] = c_state;
}

}  // namespace

extern "C" void kernel_launch(void* const* d_in, const int* in_sizes, int n_in,
                              void* d_out, int out_size, void* d_ws, size_t ws_size,
                              hipStream_t stream) {
    (void)in_sizes; (void)n_in; (void)out_size;
    const int*   tokens = (const int*)d_in[0];
    const float* emb    = (const float*)d_in[1];
    const float* Wih    = (const float*)d_in[2];
    const float* Whh    = (const float*)d_in[3];
    const float* bih    = (const float*)d_in[4];
    const float* bhh    = (const float*)d_in[5];

    const size_t need = (size_t)T_LEN * Bsz * Gg * sizeof(unsigned short);  // 134 MB
    if (ws_size >= need) {
        unsigned short* xg = (unsigned short*)d_ws;
        xg_gemm<<<T_LEN, NT, 0, stream>>>(tokens, emb, Wih, bih, bhh, xg);
        lstm_rec<<<NWG, NT, 0, stream>>>(xg, Whh, (float*)d_out);
    } else {
        lstm_fused_fb<<<NWG, NT, 0, stream>>>(tokens, emb, Wih, Whh, bih, bhh,
                                              (float*)d_out);
    }
}

// Round 4
// 1512.837 us; speedup vs baseline: 1.4847x; 1.4847x over previous
//
#include <hip/hip_runtime.h>
#include <hip/hip_bf16.h>

// LSTM encoder, two-phase.
// Phase 1 (xg_gemm, 2048 WGs): xg[t][b][hh][g] = emb[tok]·Wih^T + bias, bf16.
// Phase 2 (lstm_rec, 16 persistent WGs x 512): ONE barrier per step.
//   Each wave computes 16 MFMAs (its 16 hh-cols x 4 gate blocks), redistributes
//   gates through per-wave private LDS scratch (same-wave DS, no barrier),
//   1 activation per lane, 2B h publish, __syncthreads. xg prefetched in
//   8-step register chunks so only 1 of 8 barriers pays the vmcnt drain.

namespace {

constexpr int T_LEN = 2048;
constexpr int Bsz   = 64;
constexpr int Dd    = 128;
constexpr int Hh    = 128;
constexpr int Gg    = 512;
constexpr int NWG   = 16;
constexpr int BPW   = Bsz / NWG;  // 4
constexpr int NT    = 512;
constexpr int XS    = 136;   // hbuf row stride in shorts
constexpr int WS    = 20;    // wscr per-col stride in floats (80 B: 2-way banks)

typedef __attribute__((ext_vector_type(8))) short   short8;
typedef __attribute__((ext_vector_type(4))) float   floatx4;
typedef __attribute__((ext_vector_type(2))) unsigned int uintx2;

#define MFMA16(a, b, c) __builtin_amdgcn_mfma_f32_16x16x32_bf16((a), (b), (c), 0, 0, 0)

__device__ __forceinline__ float sigmoidf_(float x) {
    return __builtin_amdgcn_rcpf(1.0f + __builtin_amdgcn_exp2f(x * -1.44269504f));
}
__device__ __forceinline__ float tanhf_(float x) {
    return __builtin_fmaf(-2.0f,
        __builtin_amdgcn_rcpf(1.0f + __builtin_amdgcn_exp2f(x * 2.88539008f)), 1.0f);
}
__device__ __forceinline__ unsigned short f2bf(float f) {
    __hip_bfloat16 h = __float2bfloat16(f);  // RNE
    union { __hip_bfloat16 b; unsigned short u; } v; v.b = h; return v.u;
}
__device__ __forceinline__ float bf2f(unsigned int lo16) {
    union { unsigned int u; float f; } v; v.u = lo16 << 16; return v.f;
}
__device__ __forceinline__ uintx2 f4bf(const float4 v) {
    union { unsigned short us[4]; uintx2 u2; } p;
    p.us[0] = f2bf(v.x); p.us[1] = f2bf(v.y); p.us[2] = f2bf(v.z); p.us[3] = f2bf(v.w);
    return p.u2;
}
__device__ __forceinline__ short8 ld8bf(const float* p) {
    const float4 a = *reinterpret_cast<const float4*>(p);
    const float4 b = *reinterpret_cast<const float4*>(p + 4);
    short8 s;
    s[0] = (short)f2bf(a.x); s[1] = (short)f2bf(a.y);
    s[2] = (short)f2bf(a.z); s[3] = (short)f2bf(a.w);
    s[4] = (short)f2bf(b.x); s[5] = (short)f2bf(b.y);
    s[6] = (short)f2bf(b.z); s[7] = (short)f2bf(b.w);
    return s;
}

// ---------------- Phase 1: xg = emb(tok) @ Wih^T + (bih+bhh), bf16 -----------
__global__ void xg_gemm(const int*   __restrict__ tokens,
                        const float* __restrict__ emb,
                        const float* __restrict__ Wih,
                        const float* __restrict__ bih,
                        const float* __restrict__ bhh,
                        unsigned short* __restrict__ xg)  // [T][64][128][4]
{
    __shared__ unsigned short albs[64 * XS];

    const int t    = blockIdx.x;
    const int tid  = threadIdx.x;
    const int w    = tid >> 6;
    const int l    = tid & 63;
    const int quad = l >> 4;
    const int cl   = l & 15;

    {   // stage A: 64 emb rows, 8 threads/row x 16 floats
        const int b = tid >> 3, seg = tid & 7;
        const int tok = tokens[b * T_LEN + t];
        const float* src = emb + (size_t)tok * Dd + seg * 16;
        short8 lo = ld8bf(src);
        short8 hi = ld8bf(src + 8);
        *reinterpret_cast<short8*>(&albs[b * XS + seg * 16])     = lo;
        *reinterpret_cast<short8*>(&albs[b * XS + seg * 16 + 8]) = hi;
    }

    short8 wf[4][4];
    float  bias[4];
#pragma unroll
    for (int q = 0; q < 4; ++q) {
        const int n = q * 128 + w * 16 + cl;
#pragma unroll
        for (int kk = 0; kk < 4; ++kk)
            wf[q][kk] = ld8bf(Wih + n * Dd + kk * 32 + quad * 8);
        bias[q] = bih[n] + bhh[n];
    }

    __syncthreads();

    floatx4 acc[4][4];
#pragma unroll
    for (int mt = 0; mt < 4; ++mt)
#pragma unroll
        for (int q = 0; q < 4; ++q)
            acc[mt][q] = (floatx4){0.f, 0.f, 0.f, 0.f};

#pragma unroll
    for (int kk = 0; kk < 4; ++kk) {
        short8 af[4];
#pragma unroll
        for (int mt = 0; mt < 4; ++mt)
            af[mt] = *reinterpret_cast<const short8*>(
                &albs[(mt * 16 + cl) * XS + kk * 32 + quad * 8]);
#pragma unroll
        for (int mt = 0; mt < 4; ++mt)
#pragma unroll
            for (int q = 0; q < 4; ++q)
                acc[mt][q] = MFMA16(af[mt], wf[q][kk], acc[mt][q]);
    }

    const int hh = w * 16 + cl;
#pragma unroll
    for (int mt = 0; mt < 4; ++mt) {
#pragma unroll
        for (int r = 0; r < 4; ++r) {
            const int m = mt * 16 + quad * 4 + r;
            union { unsigned short us[4]; uintx2 u2; } p;
#pragma unroll
            for (int g = 0; g < 4; ++g)
                p.us[g] = f2bf(acc[mt][g][r] + bias[g]);
            *reinterpret_cast<uintx2*>(
                xg + ((size_t)t * Bsz + m) * Gg + hh * 4) = p.u2;
        }
    }
}

// ---------------- Phase 2: persistent recurrence, 1 barrier/step -------------
__global__ __launch_bounds__(NT, 2) void lstm_rec(
    const unsigned short* __restrict__ xg,   // [T][64][128][4] bf16
    const float* __restrict__ Whh,           // [512][128] fp32
    float*       __restrict__ out)           // [2][64][128] fp32
{
    __shared__ unsigned short hbuf[2][16 * XS];   // h bf16, rows 4-15 stay 0
    __shared__ float wscr[8 * 16 * WS];           // per-wave gate scratch

    const int tid  = threadIdx.x;
    const int w    = tid >> 6;
    const int l    = tid & 63;
    const int quad = l >> 4;
    const int cl   = l & 15;
    const int bbase = blockIdx.x * BPW;

    // activation mapping: lane l -> (row rr, col hh)
    const int rr = l >> 4;            // 0..3
    const int hh = w * 16 + cl;       // this wave's 16 hh cols

    // Whh B-fragments (fp32 -> bf16 once)
    short8 whh_f[4][4];
#pragma unroll
    for (int q = 0; q < 4; ++q) {
        const int n = q * 128 + w * 16 + cl;
#pragma unroll
        for (int kk = 0; kk < 4; ++kk)
            whh_f[q][kk] = ld8bf(Whh + n * Hh + kk * 32 + quad * 8);
    }

    for (int i = tid; i < 16 * XS; i += NT) { hbuf[0][i] = 0; hbuf[1][i] = 0; }

    float* wbase = &wscr[w * (16 * WS)];

    // xg chunked prefetch: 8 steps per refill
    const unsigned short* xptr = xg + (size_t)(bbase + rr) * Gg + hh * 4;
    const size_t xstride = (size_t)Bsz * Gg;   // elements per t
    uintx2 xc[8], xcn[8];
#pragma unroll
    for (int u = 0; u < 8; ++u)
        xc[u] = *reinterpret_cast<const uintx2*>(xptr + (size_t)u * xstride);

    __syncthreads();  // hbuf zeros visible

    const int afrag = cl * XS + quad * 8;  // + kk*32

    float c_state = 0.0f;
    float h_last  = 0.0f;

    for (int g = 0; g < T_LEN / 8; ++g) {
#pragma unroll
        for (int s = 0; s < 8; ++s) {
            const int cur = s & 1, nxt = cur ^ 1;   // (g*8+s)&1 == s&1

            if (s == 0) {   // refill for next group; drained at this step's barrier
                size_t tn = (size_t)(g + 1) * 8;
                if (tn >= (size_t)T_LEN) tn = 0;    // last group: dummy safe load
#pragma unroll
                for (int u = 0; u < 8; ++u)
                    xcn[u] = *reinterpret_cast<const uintx2*>(
                        xptr + (tn + u) * xstride);
            }

            // h fragments
            short8 hf[4];
#pragma unroll
            for (int kk = 0; kk < 4; ++kk)
                hf[kk] = *reinterpret_cast<const short8*>(&hbuf[cur][afrag + kk * 32]);

            floatx4 acc[4];
#pragma unroll
            for (int q = 0; q < 4; ++q) acc[q] = (floatx4){0.f, 0.f, 0.f, 0.f};
#pragma unroll
            for (int kk = 0; kk < 4; ++kk)
#pragma unroll
                for (int q = 0; q < 4; ++q)
                    acc[q] = MFMA16(hf[kk], whh_f[q][kk], acc[q]);

            // per-wave gate redistribution (same-wave DS: no barrier needed).
            // C layout: lane(quad,cl) reg r = (row quad*4+r, col w*16+cl);
            // valid rows 0..3 => quad==0 lanes hold everything.
            if (quad == 0) {
#pragma unroll
                for (int q = 0; q < 4; ++q)
                    *reinterpret_cast<floatx4*>(&wbase[cl * WS + q * 4]) = acc[q];
            }
            __builtin_amdgcn_wave_barrier();  // keep DS write->read order

            const uintx2 xv = xc[s];
            const float iv = wbase[cl * WS + 0 * 4 + rr] + bf2f(xv.x & 0xffffu);
            const float fv = wbase[cl * WS + 1 * 4 + rr] + bf2f(xv.x >> 16);
            const float gv = wbase[cl * WS + 2 * 4 + rr] + bf2f(xv.y & 0xffffu);
            const float ov = wbase[cl * WS + 3 * 4 + rr] + bf2f(xv.y >> 16);
            const float si = sigmoidf_(iv);
            const float sf = sigmoidf_(fv);
            const float so = sigmoidf_(ov);
            const float tg = tanhf_(gv);
            c_state = sf * c_state + si * tg;
            h_last  = so * tanhf_(c_state);
            hbuf[nxt][rr * XS + hh] = f2bf(h_last);

            if (s == 7) {
#pragma unroll
                for (int u = 0; u < 8; ++u) xc[u] = xcn[u];
            }
            __syncthreads();  // the ONLY barrier: h(t+1) published
        }
    }

    const int ob = (bbase + rr) * Hh + hh;
    out[ob]            = h_last;
    out[Bsz * Hh + ob] = c_state;
}

// ---------------- Fallback (R2 working kernel) if ws too small ---------------
__global__ __launch_bounds__(NT, 2) void lstm_fused_fb(
    const int*   __restrict__ tokens,
    const float* __restrict__ emb,
    const float* __restrict__ Wih,
    const float* __restrict__ Whh,
    const float* __restrict__ bih,
    const float* __restrict__ bhh,
    float*       __restrict__ out)
{
    __shared__ unsigned short xbuf[2][16 * XS];
    __shared__ unsigned short hbuf[2][16 * XS];
    __shared__ float scratch[4 * Gg];

    const int tid  = threadIdx.x;
    const int w    = tid >> 6;
    const int l    = tid & 63;
    const int quad = l >> 4;
    const int cl   = l & 15;
    const int bbase = blockIdx.x * BPW;
    const int rr = tid >> 7;
    const int hh = tid & 127;

    short8 wih[4][4], whh[4][4];
    float  bias[4];
#pragma unroll
    for (int q = 0; q < 4; ++q) {
        const int n = q * 128 + w * 16 + cl;
#pragma unroll
        for (int kk = 0; kk < 4; ++kk) {
            const int k0 = kk * 32 + quad * 8;
            wih[q][kk] = ld8bf(Wih + n * Dd + k0);
            whh[q][kk] = ld8bf(Whh + n * Hh + k0);
        }
        bias[q] = bih[n] + bhh[n];
    }

    for (int i = tid; i < 16 * XS; i += NT) {
        xbuf[0][i] = 0; xbuf[1][i] = 0; hbuf[0][i] = 0; hbuf[1][i] = 0;
    }

    const bool gact = (tid < 128);
    const int  gr = tid >> 5;
    const int  gp = tid & 31;
    float4 gdataf = {0.f, 0.f, 0.f, 0.f};
    if (gact) {
        const int tok = tokens[(bbase + gr) * T_LEN + 0];
        gdataf = *reinterpret_cast<const float4*>(emb + (size_t)tok * Dd + gp * 4);
    }
    __syncthreads();
    if (gact) *reinterpret_cast<uintx2*>(&xbuf[0][gr * XS + gp * 4]) = f4bf(gdataf);
    if (gact) {
        const int tok = tokens[(bbase + gr) * T_LEN + 1];
        gdataf = *reinterpret_cast<const float4*>(emb + (size_t)tok * Dd + gp * 4);
    }
    __syncthreads();

    const int afrag_el = cl * XS + quad * 8;

    floatx4 acc[4];
#pragma unroll
    for (int q = 0; q < 4; ++q) acc[q] = (floatx4){bias[q], bias[q], bias[q], bias[q]};
    {
        short8 xf[4];
#pragma unroll
        for (int kk = 0; kk < 4; ++kk)
            xf[kk] = *reinterpret_cast<const short8*>(&xbuf[0][afrag_el + kk * 32]);
#pragma unroll
        for (int kk = 0; kk < 4; ++kk)
#pragma unroll
            for (int q = 0; q < 4; ++q)
                acc[q] = MFMA16(xf[kk], wih[q][kk], acc[q]);
    }

    float c_state = 0.0f, h_last = 0.0f;

    for (int t = 0; t < T_LEN; ++t) {
        const int cur = t & 1, nxt = cur ^ 1;
        short8 hf[4];
#pragma unroll
        for (int kk = 0; kk < 4; ++kk)
            hf[kk] = *reinterpret_cast<const short8*>(&hbuf[cur][afrag_el + kk * 32]);
        if (gact && (t + 1 < T_LEN))
            *reinterpret_cast<uintx2*>(&xbuf[nxt][gr * XS + gp * 4]) = f4bf(gdataf);
        if (gact && (t + 2 < T_LEN)) {
            const int tok = tokens[(bbase + gr) * T_LEN + (t + 2)];
            gdataf = *reinterpret_cast<const float4*>(emb + (size_t)tok * Dd + gp * 4);
        }
#pragma unroll
        for (int kk = 0; kk < 4; ++kk)
#pragma unroll
            for (int q = 0; q < 4; ++q)
                acc[q] = MFMA16(hf[kk], whh[q][kk], acc[q]);
        if (quad == 0) {
#pragma unroll
            for (int q = 0; q < 4; ++q) {
                const int n = q * 128 + w * 16 + cl;
#pragma unroll
                for (int r = 0; r < 4; ++r)
                    scratch[r * Gg + n] = acc[q][r];
            }
        }
        __syncthreads();
#pragma unroll
        for (int q = 0; q < 4; ++q) acc[q] = (floatx4){bias[q], bias[q], bias[q], bias[q]};
        if (t + 1 < T_LEN) {
            short8 xf[4];
#pragma unroll
            for (int kk = 0; kk < 4; ++kk)
                xf[kk] = *reinterpret_cast<const short8*>(&xbuf[nxt][afrag_el + kk * 32]);
#pragma unroll
            for (int kk = 0; kk < 4; ++kk)
#pragma unroll
                for (int q = 0; q < 4; ++q)
                    acc[q] = MFMA16(xf[kk], wih[q][kk], acc[q]);
        }
        {
            const float iv = scratch[rr * Gg + hh];
            const float fv = scratch[rr * Gg + 128 + hh];
            const float gv = scratch[rr * Gg + 256 + hh];
            const float ov = scratch[rr * Gg + 384 + hh];
            const float si = sigmoidf_(iv);
            const float sf = sigmoidf_(fv);
            const float so = sigmoidf_(ov);
            const float tg = tanhf_(gv);
            c_state = sf * c_state + si * tg;
            h_last  = so * tanhf_(c_state);
            hbuf[nxt][rr * XS + hh] = f2bf(h_last);
        }
        __syncthreads();
    }

    const int ob = (bbase + rr) * Hh + hh;
    out[ob]            = h_last;
    out[Bsz * Hh + ob] = c_state;
}

}  // namespace

extern "C" void kernel_launch(void* const* d_in, const int* in_sizes, int n_in,
                              void* d_out, int out_size, void* d_ws, size_t ws_size,
                              hipStream_t stream) {
    (void)in_sizes; (void)n_in; (void)out_size;
    const int*   tokens = (const int*)d_in[0];
    const float* emb    = (const float*)d_in[1];
    const float* Wih    = (const float*)d_in[2];
    const float* Whh    = (const float*)d_in[3];
    const float* bih    = (const float*)d_in[4];
    const float* bhh    = (const float*)d_in[5];

    const size_t need = (size_t)T_LEN * Bsz * Gg * sizeof(unsigned short);  // 134 MB
    if (ws_size >= need) {
        unsigned short* xg = (unsigned short*)d_ws;
        xg_gemm<<<T_LEN, NT, 0, stream>>>(tokens, emb, Wih, bih, bhh, xg);
        lstm_rec<<<NWG, NT, 0, stream>>>(xg, Whh, (float*)d_out);
    } else {
        lstm_fused_fb<<<NWG, NT, 0, stream>>>(tokens, emb, Wih, Whh, bih, bhh,
                                              (float*)d_out);
    }
}

// Round 5
// 1441.366 us; speedup vs baseline: 1.5583x; 1.0496x over previous
//
#include <hip/hip_runtime.h>
#include <hip/hip_bf16.h>

// LSTM encoder, two-phase.
// Phase 1 (xg_gemm, 2048 WGs): xg[t][b][hh][g] = emb[tok]·Wih^T + bias, bf16.
// Phase 2 (lstm_rec_i8, 16 persistent WGs x 512): i8 MFMA recurrence.
//   h quantized to i8 (scale 127), Whh per-row i8; mfma_i32_16x16x64_i8 gives
//   K=64/inst -> 64 MFMA/WG-step (vs 128 bf16). Exact i32 accumulation.
//   Gate redistribution: in-register transpose -> 4 contiguous b128 writes
//   (quad0) + 1 b128 read/lane from per-wave scratch. One raw barrier/step
//   (s_waitcnt lgkmcnt(0); s_barrier) so xg prefetch never drains vmcnt.

namespace {

constexpr int T_LEN = 2048;
constexpr int Bsz   = 64;
constexpr int Dd    = 128;
constexpr int Hh    = 128;
constexpr int Gg    = 512;
constexpr int NWG   = 16;
constexpr int BPW   = Bsz / NWG;  // 4
constexpr int NT    = 512;
constexpr int XS    = 136;   // bf16 LDS row stride (phase 1 / fallback)
constexpr int HS    = 144;   // i8 hbuf row stride in bytes

typedef __attribute__((ext_vector_type(8))) short   short8;
typedef __attribute__((ext_vector_type(4))) float   floatx4;
typedef __attribute__((ext_vector_type(4))) int     intx4;
typedef __attribute__((ext_vector_type(2))) unsigned int uintx2;

#define MFMA16(a, b, c) __builtin_amdgcn_mfma_f32_16x16x32_bf16((a), (b), (c), 0, 0, 0)

__device__ __forceinline__ float sigmoidf_(float x) {
    return __builtin_amdgcn_rcpf(1.0f + __builtin_amdgcn_exp2f(x * -1.44269504f));
}
__device__ __forceinline__ float tanhf_(float x) {
    return __builtin_fmaf(-2.0f,
        __builtin_amdgcn_rcpf(1.0f + __builtin_amdgcn_exp2f(x * 2.88539008f)), 1.0f);
}
__device__ __forceinline__ unsigned short f2bf(float f) {
    __hip_bfloat16 h = __float2bfloat16(f);  // RNE
    union { __hip_bfloat16 b; unsigned short u; } v; v.b = h; return v.u;
}
__device__ __forceinline__ float bf2f(unsigned int lo16) {
    union { unsigned int u; float f; } v; v.u = lo16 << 16; return v.f;
}
__device__ __forceinline__ uintx2 f4bf(const float4 v) {
    union { unsigned short us[4]; uintx2 u2; } p;
    p.us[0] = f2bf(v.x); p.us[1] = f2bf(v.y); p.us[2] = f2bf(v.z); p.us[3] = f2bf(v.w);
    return p.u2;
}
__device__ __forceinline__ short8 ld8bf(const float* p) {
    const float4 a = *reinterpret_cast<const float4*>(p);
    const float4 b = *reinterpret_cast<const float4*>(p + 4);
    short8 s;
    s[0] = (short)f2bf(a.x); s[1] = (short)f2bf(a.y);
    s[2] = (short)f2bf(a.z); s[3] = (short)f2bf(a.w);
    s[4] = (short)f2bf(b.x); s[5] = (short)f2bf(b.y);
    s[6] = (short)f2bf(b.z); s[7] = (short)f2bf(b.w);
    return s;
}
// barrier without the compiler's vmcnt(0) drain: LDS-visibility only
__device__ __forceinline__ void lds_barrier() {
    asm volatile("s_waitcnt lgkmcnt(0)\n\ts_barrier" ::: "memory");
}

// ---------------- Phase 1: xg = emb(tok) @ Wih^T + (bih+bhh), bf16 -----------
__global__ void xg_gemm(const int*   __restrict__ tokens,
                        const float* __restrict__ emb,
                        const float* __restrict__ Wih,
                        const float* __restrict__ bih,
                        const float* __restrict__ bhh,
                        unsigned short* __restrict__ xg)  // [T][64][128][4]
{
    __shared__ unsigned short albs[64 * XS];

    const int t    = blockIdx.x;
    const int tid  = threadIdx.x;
    const int w    = tid >> 6;
    const int l    = tid & 63;
    const int quad = l >> 4;
    const int cl   = l & 15;

    {   // stage A: 64 emb rows, 8 threads/row x 16 floats
        const int b = tid >> 3, seg = tid & 7;
        const int tok = tokens[b * T_LEN + t];
        const float* src = emb + (size_t)tok * Dd + seg * 16;
        short8 lo = ld8bf(src);
        short8 hi = ld8bf(src + 8);
        *reinterpret_cast<short8*>(&albs[b * XS + seg * 16])     = lo;
        *reinterpret_cast<short8*>(&albs[b * XS + seg * 16 + 8]) = hi;
    }

    short8 wf[4][4];
    float  bias[4];
#pragma unroll
    for (int q = 0; q < 4; ++q) {
        const int n = q * 128 + w * 16 + cl;
#pragma unroll
        for (int kk = 0; kk < 4; ++kk)
            wf[q][kk] = ld8bf(Wih + n * Dd + kk * 32 + quad * 8);
        bias[q] = bih[n] + bhh[n];
    }

    __syncthreads();

    floatx4 acc[4][4];
#pragma unroll
    for (int mt = 0; mt < 4; ++mt)
#pragma unroll
        for (int q = 0; q < 4; ++q)
            acc[mt][q] = (floatx4){0.f, 0.f, 0.f, 0.f};

#pragma unroll
    for (int kk = 0; kk < 4; ++kk) {
        short8 af[4];
#pragma unroll
        for (int mt = 0; mt < 4; ++mt)
            af[mt] = *reinterpret_cast<const short8*>(
                &albs[(mt * 16 + cl) * XS + kk * 32 + quad * 8]);
#pragma unroll
        for (int mt = 0; mt < 4; ++mt)
#pragma unroll
            for (int q = 0; q < 4; ++q)
                acc[mt][q] = MFMA16(af[mt], wf[q][kk], acc[mt][q]);
    }

    const int hh = w * 16 + cl;
#pragma unroll
    for (int mt = 0; mt < 4; ++mt) {
#pragma unroll
        for (int r = 0; r < 4; ++r) {
            const int m = mt * 16 + quad * 4 + r;
            union { unsigned short us[4]; uintx2 u2; } p;
#pragma unroll
            for (int g = 0; g < 4; ++g)
                p.us[g] = f2bf(acc[mt][g][r] + bias[g]);
            *reinterpret_cast<uintx2*>(
                xg + ((size_t)t * Bsz + m) * Gg + hh * 4) = p.u2;
        }
    }
}

// ---------------- Phase 2: persistent recurrence, i8 MFMA --------------------
__global__ __launch_bounds__(NT, 2) void lstm_rec_i8(
    const unsigned short* __restrict__ xg,   // [T][64][128][4] bf16
    const float* __restrict__ Whh,           // [512][128] fp32
    float*       __restrict__ out)           // [2][64][128] fp32
{
    __shared__ __align__(16) unsigned char hq[2][16 * HS];  // h i8, rows 4-15 = 0
    __shared__ float wscr[8][256];                          // per-wave gate scratch

    const int tid  = threadIdx.x;
    const int w    = tid >> 6;
    const int l    = tid & 63;
    const int quad = l >> 4;
    const int cl   = l & 15;
    const int bbase = blockIdx.x * BPW;

    const int rr = l >> 4;            // activation: row 0..3
    const int hh = w * 16 + cl;       // this wave's 16 hh cols

    // ---- Whh per-row i8 quantization; fragments k = kk*64 + quad*16 + j ----
    intx4 wq[4][2];
    float dq[4];
#pragma unroll
    for (int q = 0; q < 4; ++q) {
        const int n = q * 128 + w * 16 + cl;
        const float* wr = Whh + n * Hh;
        float am = 0.f;
#pragma unroll 8
        for (int k = 0; k < 128; k += 4) {
            const float4 v = *reinterpret_cast<const float4*>(wr + k);
            am = fmaxf(am, fmaxf(fmaxf(fabsf(v.x), fabsf(v.y)),
                                 fmaxf(fabsf(v.z), fabsf(v.w))));
        }
        const float swm = fmaxf(am, 1e-20f);
        dq[q] = swm * (1.0f / (127.0f * 127.0f));
        const float inv = 127.0f / swm;
#pragma unroll
        for (int kk = 0; kk < 2; ++kk) {
            int e[4];
#pragma unroll
            for (int g4 = 0; g4 < 4; ++g4) {
                const int kb = kk * 64 + quad * 16 + g4 * 4;
                const int b0 = (int)__builtin_rintf(wr[kb + 0] * inv);
                const int b1 = (int)__builtin_rintf(wr[kb + 1] * inv);
                const int b2 = (int)__builtin_rintf(wr[kb + 2] * inv);
                const int b3 = (int)__builtin_rintf(wr[kb + 3] * inv);
                e[g4] = (b0 & 0xff) | ((b1 & 0xff) << 8) |
                        ((b2 & 0xff) << 16) | ((b3 & 0xff) << 24);
            }
            wq[q][kk] = (intx4){e[0], e[1], e[2], e[3]};
        }
    }

    // zero h buffers (rows 4-15 must stay 0 forever)
    for (int i = tid; i < 2 * 16 * HS; i += NT)
        (&hq[0][0])[i] = 0;

    // xg chunked prefetch: 8 steps per refill
    const unsigned short* xptr = xg + (size_t)(bbase + rr) * Gg + hh * 4;
    const size_t xstride = (size_t)Bsz * Gg;
    uintx2 xc[8], xcn[8];
#pragma unroll
    for (int u = 0; u < 8; ++u)
        xc[u] = *reinterpret_cast<const uintx2*>(xptr + (size_t)u * xstride);

    __syncthreads();  // hq zeros visible (full barrier once)

    float c_state = 0.0f;
    float h_last  = 0.0f;

    for (int g = 0; g < T_LEN / 8; ++g) {
#pragma unroll
        for (int s = 0; s < 8; ++s) {
            const int cur = s & 1, nxt = cur ^ 1;

            if (s == 0) {   // refill next group; no vmcnt drain at barriers
                size_t tn = (size_t)(g + 1) * 8;
                if (tn >= (size_t)T_LEN) tn = 0;
#pragma unroll
                for (int u = 0; u < 8; ++u)
                    xcn[u] = *reinterpret_cast<const uintx2*>(
                        xptr + (tn + u) * xstride);
            }

            // h A-fragments: 2 x b128 per lane (row cl, k-slices)
            const intx4 hf0 = *reinterpret_cast<const intx4*>(
                &hq[cur][cl * HS + quad * 16]);
            const intx4 hf1 = *reinterpret_cast<const intx4*>(
                &hq[cur][cl * HS + quad * 16 + 64]);

            intx4 acc[4];
#pragma unroll
            for (int q = 0; q < 4; ++q)
                acc[q] = __builtin_amdgcn_mfma_i32_16x16x64_i8(
                    hf0, wq[q][0], (intx4){0, 0, 0, 0}, 0, 0, 0);
#pragma unroll
            for (int q = 0; q < 4; ++q)
                acc[q] = __builtin_amdgcn_mfma_i32_16x16x64_i8(
                    hf1, wq[q][1], acc[q], 0, 0, 0);

            // dequant + in-register transpose -> wave-private scratch.
            // C layout: lane(quad,cl) reg r = (row quad*4+r, col w*16+cl);
            // valid rows 0..3 => quad==0 holds everything.
            if (quad == 0) {
#pragma unroll
                for (int r = 0; r < 4; ++r) {
                    float4 v;
                    v.x = (float)acc[0][r] * dq[0];
                    v.y = (float)acc[1][r] * dq[1];
                    v.z = (float)acc[2][r] * dq[2];
                    v.w = (float)acc[3][r] * dq[3];
                    *reinterpret_cast<float4*>(&wscr[w][(r * 16 + cl) * 4]) = v;
                }
            }
            __builtin_amdgcn_wave_barrier();  // DS in-order within wave

            const float4 gq = *reinterpret_cast<const float4*>(&wscr[w][l * 4]);
            const uintx2 xv = xc[s];
            const float iv = gq.x + bf2f(xv.x & 0xffffu);
            const float fv = gq.y + bf2f(xv.x >> 16);
            const float gv = gq.z + bf2f(xv.y & 0xffffu);
            const float ov = gq.w + bf2f(xv.y >> 16);
            const float si = sigmoidf_(iv);
            const float sf = sigmoidf_(fv);
            const float so = sigmoidf_(ov);
            const float tg = tanhf_(gv);
            c_state = sf * c_state + si * tg;
            h_last  = so * tanhf_(c_state);
            // publish h as i8 (|h|<1 so no clamp needed)
            hq[nxt][rr * HS + hh] =
                (unsigned char)(((int)__builtin_rintf(h_last * 127.0f)) & 0xff);

            if (s == 7) {
#pragma unroll
                for (int u = 0; u < 8; ++u) xc[u] = xcn[u];
            }
            lds_barrier();  // LDS-only barrier: h(t+1) visible, no vmcnt drain
        }
    }

    const int ob = (bbase + rr) * Hh + hh;
    out[ob]            = h_last;
    out[Bsz * Hh + ob] = c_state;
}

// ---------------- Fallback (R2 working kernel) if ws too small ---------------
__global__ __launch_bounds__(NT, 2) void lstm_fused_fb(
    const int*   __restrict__ tokens,
    const float* __restrict__ emb,
    const float* __restrict__ Wih,
    const float* __restrict__ Whh,
    const float* __restrict__ bih,
    const float* __restrict__ bhh,
    float*       __restrict__ out)
{
    __shared__ unsigned short xbuf[2][16 * XS];
    __shared__ unsigned short hbuf[2][16 * XS];
    __shared__ float scratch[4 * Gg];

    const int tid  = threadIdx.x;
    const int w    = tid >> 6;
    const int l    = tid & 63;
    const int quad = l >> 4;
    const int cl   = l & 15;
    const int bbase = blockIdx.x * BPW;
    const int rr = tid >> 7;
    const int hh = tid & 127;

    short8 wih[4][4], whh[4][4];
    float  bias[4];
#pragma unroll
    for (int q = 0; q < 4; ++q) {
        const int n = q * 128 + w * 16 + cl;
#pragma unroll
        for (int kk = 0; kk < 4; ++kk) {
            const int k0 = kk * 32 + quad * 8;
            wih[q][kk] = ld8bf(Wih + n * Dd + k0);
            whh[q][kk] = ld8bf(Whh + n * Hh + k0);
        }
        bias[q] = bih[n] + bhh[n];
    }

    for (int i = tid; i < 16 * XS; i += NT) {
        xbuf[0][i] = 0; xbuf[1][i] = 0; hbuf[0][i] = 0; hbuf[1][i] = 0;
    }

    const bool gact = (tid < 128);
    const int  gr = tid >> 5;
    const int  gp = tid & 31;
    float4 gdataf = {0.f, 0.f, 0.f, 0.f};
    if (gact) {
        const int tok = tokens[(bbase + gr) * T_LEN + 0];
        gdataf = *reinterpret_cast<const float4*>(emb + (size_t)tok * Dd + gp * 4);
    }
    __syncthreads();
    if (gact) *reinterpret_cast<uintx2*>(&xbuf[0][gr * XS + gp * 4]) = f4bf(gdataf);
    if (gact) {
        const int tok = tokens[(bbase + gr) * T_LEN + 1];
        gdataf = *reinterpret_cast<const float4*>(emb + (size_t)tok * Dd + gp * 4);
    }
    __syncthreads();

    const int afrag_el = cl * XS + quad * 8;

    floatx4 acc[4];
#pragma unroll
    for (int q = 0; q < 4; ++q) acc[q] = (floatx4){bias[q], bias[q], bias[q], bias[q]};
    {
        short8 xf[4];
#pragma unroll
        for (int kk = 0; kk < 4; ++kk)
            xf[kk] = *reinterpret_cast<const short8*>(&xbuf[0][afrag_el + kk * 32]);
#pragma unroll
        for (int kk = 0; kk < 4; ++kk)
#pragma unroll
            for (int q = 0; q < 4; ++q)
                acc[q] = MFMA16(xf[kk], wih[q][kk], acc[q]);
    }

    float c_state = 0.0f, h_last = 0.0f;

    for (int t = 0; t < T_LEN; ++t) {
        const int cur = t & 1, nxt = cur ^ 1;
        short8 hf[4];
#pragma unroll
        for (int kk = 0; kk < 4; ++kk)
            hf[kk] = *reinterpret_cast<const short8*>(&hbuf[cur][afrag_el + kk * 32]);
        if (gact && (t + 1 < T_LEN))
            *reinterpret_cast<uintx2*>(&xbuf[nxt][gr * XS + gp * 4]) = f4bf(gdataf);
        if (gact && (t + 2 < T_LEN)) {
            const int tok = tokens[(bbase + gr) * T_LEN + (t + 2)];
            gdataf = *reinterpret_cast<const float4*>(emb + (size_t)tok * Dd + gp * 4);
        }
#pragma unroll
        for (int kk = 0; kk < 4; ++kk)
#pragma unroll
            for (int q = 0; q < 4; ++q)
                acc[q] = MFMA16(hf[kk], whh[q][kk], acc[q]);
        if (quad == 0) {
#pragma unroll
            for (int q = 0; q < 4; ++q) {
                const int n = q * 128 + w * 16 + cl;
#pragma unroll
                for (int r = 0; r < 4; ++r)
                    scratch[r * Gg + n] = acc[q][r];
            }
        }
        __syncthreads();
#pragma unroll
        for (int q = 0; q < 4; ++q) acc[q] = (floatx4){bias[q], bias[q], bias[q], bias[q]};
        if (t + 1 < T_LEN) {
            short8 xf[4];
#pragma unroll
            for (int kk = 0; kk < 4; ++kk)
                xf[kk] = *reinterpret_cast<const short8*>(&xbuf[nxt][afrag_el + kk * 32]);
#pragma unroll
            for (int kk = 0; kk < 4; ++kk)
#pragma unroll
                for (int q = 0; q < 4; ++q)
                    acc[q] = MFMA16(xf[kk], wih[q][kk], acc[q]);
        }
        {
            const float iv = scratch[rr * Gg + hh];
            const float fv = scratch[rr * Gg + 128 + hh];
            const float gv = scratch[rr * Gg + 256 + hh];
            const float ov = scratch[rr * Gg + 384 + hh];
            const float si = sigmoidf_(iv);
            const float sf = sigmoidf_(fv);
            const float so = sigmoidf_(ov);
            const float tg = tanhf_(gv);
            c_state = sf * c_state + si * tg;
            h_last  = so * tanhf_(c_state);
            hbuf[nxt][rr * XS + hh] = f2bf(h_last);
        }
        __syncthreads();
    }

    const int ob = (bbase + rr) * Hh + hh;
    out[ob]            = h_last;
    out[Bsz * Hh + ob] = c_state;
}

}  // namespace

extern "C" void kernel_launch(void* const* d_in, const int* in_sizes, int n_in,
                              void* d_out, int out_size, void* d_ws, size_t ws_size,
                              hipStream_t stream) {
    (void)in_sizes; (void)n_in; (void)out_size;
    const int*   tokens = (const int*)d_in[0];
    const float* emb    = (const float*)d_in[1];
    const float* Wih    = (const float*)d_in[2];
    const float* Whh    = (const float*)d_in[3];
    const float* bih    = (const float*)d_in[4];
    const float* bhh    = (const float*)d_in[5];

    const size_t need = (size_t)T_LEN * Bsz * Gg * sizeof(unsigned short);  // 134 MB
    if (ws_size >= need) {
        unsigned short* xg = (unsigned short*)d_ws;
        xg_gemm<<<T_LEN, NT, 0, stream>>>(tokens, emb, Wih, bih, bhh, xg);
        lstm_rec_i8<<<NWG, NT, 0, stream>>>(xg, Whh, (float*)d_out);
    } else {
        lstm_fused_fb<<<NWG, NT, 0, stream>>>(tokens, emb, Wih, Whh, bih, bhh,
                                              (float*)d_out);
    }
}